// Round 1
// baseline (837.515 us; speedup 1.0000x reference)
//
#include <hip/hip_runtime.h>

// Problem constants (from reference): z (64,128,64,64) f32, emb (256,128) f32
#define K_EMB   256
#define C_DIM   128
#define HW      4096            // 64*64
#define NPOS    262144          // 64*HW
#define Q_ELEMS 33554432        // 64*128*64*64
#define IDX_OFF Q_ELEMS         // idx chunk offset in d_out (floats)
#define LOSS_OFF (Q_ELEMS + NPOS)

// ws layout (floats): [0,256) enorm, [256] loss accumulator, [512, 512+32768) embT (c*256+k)
#define WS_ENORM 0
#define WS_ACC   256
#define WS_EMBT  512
#define WS_NEED_BASIC ((WS_EMBT) * 4)                 // bytes for enorm+acc
#define WS_NEED_FULL  ((WS_EMBT + C_DIM * K_EMB) * 4) // + embT

// ---------------------------------------------------------------------------
// Kernel 0: per-code squared norms, optional emb transpose, zero loss accum.
// ---------------------------------------------------------------------------
__global__ __launch_bounds__(K_EMB) void vq_prep(const float* __restrict__ emb,
                                                 float* __restrict__ ws,
                                                 int use_embT) {
    int k = threadIdx.x;  // 256 threads, 1 block
    float s = 0.f;
    #pragma unroll 8
    for (int c = 0; c < C_DIM; ++c) {
        float e = emb[k * C_DIM + c];
        s = fmaf(e, e, s);
        if (use_embT) ws[WS_EMBT + c * K_EMB + k] = e;
    }
    ws[WS_ENORM + k] = s;
    if (k == 0) ws[WS_ACC] = 0.f;
}

// ---------------------------------------------------------------------------
// Kernel 1: main VQ. One wave (64 lanes) per block, one position per lane.
// Lane holds the full 128-dim z vector in VGPRs; codebook rows are read with
// wave-uniform indices -> scalar (SMEM) loads, broadcast to all lanes.
// Inner loop is pure v_fmac_f32 (VGPR x SGPR). No LDS.
// ---------------------------------------------------------------------------
__global__ __launch_bounds__(64) void vq_main(const float* __restrict__ z,
                                              const float* __restrict__ emb,
                                              const float* __restrict__ ws,
                                              float* __restrict__ out,
                                              float* __restrict__ loss_acc,
                                              int use_embT) {
    const int lane = threadIdx.x;
    const int pos  = blockIdx.x * 64 + lane;       // flat (b, h, w)
    const int b    = pos >> 12;                    // / 4096
    const int hw   = pos & 4095;

    const float* zp = z + (size_t)b * (C_DIM * HW) + hw;

    // Load this lane's position vector (coalesced across lanes per c).
    float zr[C_DIM];
    #pragma unroll
    for (int c = 0; c < C_DIM; ++c) zr[c] = zp[(size_t)c * HW];

    float znorm = 0.f;
    #pragma unroll
    for (int c = 0; c < C_DIM; ++c) znorm = fmaf(zr[c], zr[c], znorm);

    // Argmin over codes; d = (||z||^2 - 2 z.e) + ||e||^2 (reference formula).
    float best = 3.402823466e38f;
    int bidx = 0;
    #pragma unroll 1
    for (int k = 0; k < K_EMB; ++k) {
        const float* __restrict__ ek = emb + k * C_DIM;  // wave-uniform row
        float acc = 0.f;
        #pragma unroll
        for (int c = 0; c < C_DIM; ++c) acc = fmaf(zr[c], ek[c], acc);
        float d = (znorm - 2.0f * acc) + ws[WS_ENORM + k];
        if (d < best) { best = d; bidx = k; }   // strict < = first-min tiebreak
    }

    out[IDX_OFF + pos] = (float)bidx;

    // Epilogue: quantized_ste = z + (e - z), accumulate (e - z)^2.
    float lsum = 0.f;
    float* qp = out + (size_t)b * (C_DIM * HW) + hw;
    if (use_embT) {
        const float* __restrict__ embT = ws + WS_EMBT;
        #pragma unroll 8
        for (int c = 0; c < C_DIM; ++c) {
            float e  = embT[c * K_EMB + bidx];
            float dq = e - zr[c];
            lsum = fmaf(dq, dq, lsum);
            qp[(size_t)c * HW] = zr[c] + dq;
        }
    } else {
        #pragma unroll 8
        for (int c = 0; c < C_DIM; ++c) {
            float e  = emb[bidx * C_DIM + c];
            float dq = e - zr[c];
            lsum = fmaf(dq, dq, lsum);
            qp[(size_t)c * HW] = zr[c] + dq;
        }
    }

    // Wave-level reduction, one atomic per wave.
    #pragma unroll
    for (int off = 32; off > 0; off >>= 1)
        lsum += __shfl_down(lsum, off, 64);
    if (lane == 0) atomicAdd(loss_acc, lsum);
}

// ---------------------------------------------------------------------------
// Kernel 2: finalize the two scalar losses.
// ---------------------------------------------------------------------------
__global__ void vq_finalize(const float* __restrict__ loss_acc,
                            float* __restrict__ out_losses) {
    float S = loss_acc[0];
    float mean = S / (float)Q_ELEMS;
    out_losses[0] = 0.25f * mean;  // commitment_loss
    out_losses[1] = mean;          // codebook_loss
}

extern "C" void kernel_launch(void* const* d_in, const int* in_sizes, int n_in,
                              void* d_out, int out_size, void* d_ws, size_t ws_size,
                              hipStream_t stream) {
    const float* z   = (const float*)d_in[0];
    const float* emb = (const float*)d_in[1];
    float* out = (float*)d_out;
    float* ws  = (float*)d_ws;

    int use_embT = (ws_size >= (size_t)WS_NEED_FULL) ? 1 : 0;

    vq_prep<<<1, K_EMB, 0, stream>>>(emb, ws, use_embT);
    vq_main<<<NPOS / 64, 64, 0, stream>>>(z, emb, ws, out, ws + WS_ACC, use_embT);
    vq_finalize<<<1, 1, 0, stream>>>(ws + WS_ACC, out + LOSS_OFF);
}

// Round 2
// 830.515 us; speedup vs baseline: 1.0084x; 1.0084x over previous
//
#include <hip/hip_runtime.h>

// Problem constants (from reference): z (64,128,64,64) f32, emb (256,128) f32
#define K_EMB   256
#define C_DIM   128
#define HW      4096            // 64*64
#define NPOS    262144          // 64*HW
#define Q_ELEMS 33554432        // 64*128*64*64
#define IDX_OFF Q_ELEMS         // idx chunk offset in d_out (floats)
#define LOSS_OFF (Q_ELEMS + NPOS)

// ws layout (floats): [0,256) enorm, [256] loss accumulator, [512, 512+32768) embT (c*256+k)
#define WS_ENORM 0
#define WS_ACC   256
#define WS_EMBT  512
#define WS_NEED_FULL  ((WS_EMBT + C_DIM * K_EMB) * 4)

// ---------------------------------------------------------------------------
// Kernel 0: per-code squared norms, optional emb transpose, zero loss accum.
// ---------------------------------------------------------------------------
__global__ __launch_bounds__(K_EMB) void vq_prep(const float* __restrict__ emb,
                                                 float* __restrict__ ws,
                                                 int use_embT) {
    int k = threadIdx.x;  // 256 threads, 1 block
    float s = 0.f;
    #pragma unroll 8
    for (int c = 0; c < C_DIM; ++c) {
        float e = emb[k * C_DIM + c];
        s = fmaf(e, e, s);
        if (use_embT) ws[WS_EMBT + c * K_EMB + k] = e;
    }
    ws[WS_ENORM + k] = s;
    if (k == 0) ws[WS_ACC] = 0.f;
}

// ---------------------------------------------------------------------------
// Kernel 1: main VQ. One wave per block, one position per lane.
// zr[128] MUST stay in VGPRs: __launch_bounds__(64, 2) caps at 256 VGPRs
// (min 2 waves/EU) -- bare (64) let the compiler spill zr to scratch in R1
// (WRITE_SIZE showed +134 MB spill traffic, VALUBusy 36%).
// Codebook rows are wave-uniform -> s_load broadcast; inner loop is
// v_fmac_f32 (VGPR x SGPR). No LDS.
// ---------------------------------------------------------------------------
__global__ __launch_bounds__(64, 2) void vq_main(const float* __restrict__ z,
                                                 const float* __restrict__ emb,
                                                 const float* __restrict__ ws,
                                                 float* __restrict__ out,
                                                 float* __restrict__ loss_acc,
                                                 int use_embT) {
    const int lane = threadIdx.x;
    const int pos  = blockIdx.x * 64 + lane;       // flat (b, h, w)
    const int b    = pos >> 12;                    // / 4096
    const int hw   = pos & 4095;

    const float* zp = z + (size_t)b * (C_DIM * HW) + hw;

    // Load this lane's position vector (coalesced across lanes per c).
    float zr[C_DIM];
    #pragma unroll
    for (int c = 0; c < C_DIM; ++c) zr[c] = zp[(size_t)c * HW];

    float znorm = 0.f;
    #pragma unroll
    for (int c = 0; c < C_DIM; ++c) znorm = fmaf(zr[c], zr[c], znorm);

    // Argmin over codes; d = (||z||^2 - 2 z.e) + ||e||^2 (reference formula).
    // k unrolled x2 so the compiler can prefetch row k+1's s_loads behind
    // row k's 128 FMAs.
    float best = 3.402823466e38f;
    int bidx = 0;
    #pragma unroll 2
    for (int k = 0; k < K_EMB; ++k) {
        const float* __restrict__ ek = emb + k * C_DIM;  // wave-uniform row
        float acc = 0.f;
        #pragma unroll
        for (int c = 0; c < C_DIM; ++c) acc = fmaf(zr[c], ek[c], acc);
        float d = (znorm - 2.0f * acc) + ws[WS_ENORM + k];
        if (d < best) { best = d; bidx = k; }   // strict < = first-min tiebreak
    }

    out[IDX_OFF + pos] = (float)bidx;

    // Epilogue: quantized_ste = z + (e - z), accumulate (e - z)^2.
    float lsum = 0.f;
    float* qp = out + (size_t)b * (C_DIM * HW) + hw;
    if (use_embT) {
        const float* __restrict__ embT = ws + WS_EMBT;
        #pragma unroll 8
        for (int c = 0; c < C_DIM; ++c) {
            float e  = embT[c * K_EMB + bidx];
            float dq = e - zr[c];
            lsum = fmaf(dq, dq, lsum);
            qp[(size_t)c * HW] = zr[c] + dq;
        }
    } else {
        #pragma unroll 8
        for (int c = 0; c < C_DIM; ++c) {
            float e  = emb[bidx * C_DIM + c];
            float dq = e - zr[c];
            lsum = fmaf(dq, dq, lsum);
            qp[(size_t)c * HW] = zr[c] + dq;
        }
    }

    // Wave-level reduction, one atomic per wave.
    #pragma unroll
    for (int off = 32; off > 0; off >>= 1)
        lsum += __shfl_down(lsum, off, 64);
    if (lane == 0) atomicAdd(loss_acc, lsum);
}

// ---------------------------------------------------------------------------
// Kernel 2: finalize the two scalar losses.
// ---------------------------------------------------------------------------
__global__ void vq_finalize(const float* __restrict__ loss_acc,
                            float* __restrict__ out_losses) {
    float S = loss_acc[0];
    float mean = S / (float)Q_ELEMS;
    out_losses[0] = 0.25f * mean;  // commitment_loss
    out_losses[1] = mean;          // codebook_loss
}

extern "C" void kernel_launch(void* const* d_in, const int* in_sizes, int n_in,
                              void* d_out, int out_size, void* d_ws, size_t ws_size,
                              hipStream_t stream) {
    const float* z   = (const float*)d_in[0];
    const float* emb = (const float*)d_in[1];
    float* out = (float*)d_out;
    float* ws  = (float*)d_ws;

    int use_embT = (ws_size >= (size_t)WS_NEED_FULL) ? 1 : 0;

    vq_prep<<<1, K_EMB, 0, stream>>>(emb, ws, use_embT);
    vq_main<<<NPOS / 64, 64, 0, stream>>>(z, emb, ws, out, ws + WS_ACC, use_embT);
    vq_finalize<<<1, 1, 0, stream>>>(ws + WS_ACC, out + LOSS_OFF);
}

// Round 3
// 808.149 us; speedup vs baseline: 1.0363x; 1.0277x over previous
//
#include <hip/hip_runtime.h>

// Problem constants (from reference): z (64,128,64,64) f32, emb (256,128) f32
#define K_EMB   256
#define C_DIM   128
#define HW      4096            // 64*64
#define NPOS    262144          // 64*HW
#define Q_ELEMS 33554432        // 64*128*64*64
#define IDX_OFF Q_ELEMS         // idx chunk offset in d_out (floats)
#define LOSS_OFF (Q_ELEMS + NPOS)

// ws layout (floats): [0,256) enorm, [256] loss accumulator, [512, 512+32768) embT (c*256+k)
#define WS_ENORM 0
#define WS_ACC   256
#define WS_EMBT  512
#define WS_NEED_FULL  ((WS_EMBT + C_DIM * K_EMB) * 4)

// ---------------------------------------------------------------------------
// Kernel 0: per-code squared norms, optional emb transpose, zero loss accum.
// ---------------------------------------------------------------------------
__global__ __launch_bounds__(K_EMB) void vq_prep(const float* __restrict__ emb,
                                                 float* __restrict__ ws,
                                                 int use_embT) {
    int k = threadIdx.x;  // 256 threads, 1 block
    float s = 0.f;
    #pragma unroll 8
    for (int c = 0; c < C_DIM; ++c) {
        float e = emb[k * C_DIM + c];
        s = fmaf(e, e, s);
        if (use_embT) ws[WS_EMBT + c * K_EMB + k] = e;
    }
    ws[WS_ENORM + k] = s;
    if (k == 0) ws[WS_ACC] = 0.f;
}

// ---------------------------------------------------------------------------
// Kernel 1: main VQ. One wave per block, one position per lane.
//
// CRITICAL: every zr[] access must use a COMPILE-TIME index. In R1/R2 the
// epilogue used `#pragma unroll 8` (partial) -> runtime index into zr ->
// the compiler demoted zr[128] to scratch for the WHOLE kernel (VGPR=72,
// +134 MB spill WRITE traffic, VALUBusy 40%). All loops touching zr are
// now fully unrolled. __launch_bounds__(64,2) gives the allocator a
// 256-VGPR budget (2 waves/EU min).
// ---------------------------------------------------------------------------
__global__ __launch_bounds__(64, 2) void vq_main(const float* __restrict__ z,
                                                 const float* __restrict__ emb,
                                                 const float* __restrict__ ws,
                                                 float* __restrict__ out,
                                                 float* __restrict__ loss_acc,
                                                 int use_embT) {
    const int lane = threadIdx.x;
    const int pos  = blockIdx.x * 64 + lane;       // flat (b, h, w)
    const int b    = pos >> 12;                    // / 4096
    const int hw   = pos & 4095;

    const float* zp = z + (size_t)b * (C_DIM * HW) + hw;

    // Load this lane's position vector (coalesced across lanes per c).
    float zr[C_DIM];
    #pragma unroll
    for (int c = 0; c < C_DIM; ++c) zr[c] = zp[(size_t)c * HW];

    float znorm = 0.f;
    #pragma unroll
    for (int c = 0; c < C_DIM; ++c) znorm = fmaf(zr[c], zr[c], znorm);

    // Argmin over codes; d = (||z||^2 - 2 z.e) + ||e||^2 (reference formula).
    // k unrolled x2 so the compiler can prefetch row k+1's s_loads behind
    // row k's 128 FMAs. zr indices inside are compile-time (inner loop
    // fully unrolled).
    float best = 3.402823466e38f;
    int bidx = 0;
    #pragma unroll 2
    for (int k = 0; k < K_EMB; ++k) {
        const float* __restrict__ ek = emb + k * C_DIM;  // wave-uniform row
        float acc = 0.f;
        #pragma unroll
        for (int c = 0; c < C_DIM; ++c) acc = fmaf(zr[c], ek[c], acc);
        float d = (znorm - 2.0f * acc) + ws[WS_ENORM + k];
        if (d < best) { best = d; bidx = k; }   // strict < = first-min tiebreak
    }

    out[IDX_OFF + pos] = (float)bidx;

    // Epilogue: quantized_ste = z + (e - z), accumulate (e - z)^2.
    // FULLY unrolled (compile-time zr indices -- see header comment).
    float lsum = 0.f;
    float* qp = out + (size_t)b * (C_DIM * HW) + hw;
    if (use_embT) {
        const float* __restrict__ embT = ws + WS_EMBT;
        #pragma unroll
        for (int c = 0; c < C_DIM; ++c) {
            float e  = embT[c * K_EMB + bidx];
            float dq = e - zr[c];
            lsum = fmaf(dq, dq, lsum);
            qp[(size_t)c * HW] = zr[c] + dq;
        }
    } else {
        #pragma unroll
        for (int c = 0; c < C_DIM; ++c) {
            float e  = emb[bidx * C_DIM + c];
            float dq = e - zr[c];
            lsum = fmaf(dq, dq, lsum);
            qp[(size_t)c * HW] = zr[c] + dq;
        }
    }

    // Wave-level reduction, one atomic per wave.
    #pragma unroll
    for (int off = 32; off > 0; off >>= 1)
        lsum += __shfl_down(lsum, off, 64);
    if (lane == 0) atomicAdd(loss_acc, lsum);
}

// ---------------------------------------------------------------------------
// Kernel 2: finalize the two scalar losses.
// ---------------------------------------------------------------------------
__global__ void vq_finalize(const float* __restrict__ loss_acc,
                            float* __restrict__ out_losses) {
    float S = loss_acc[0];
    float mean = S / (float)Q_ELEMS;
    out_losses[0] = 0.25f * mean;  // commitment_loss
    out_losses[1] = mean;          // codebook_loss
}

extern "C" void kernel_launch(void* const* d_in, const int* in_sizes, int n_in,
                              void* d_out, int out_size, void* d_ws, size_t ws_size,
                              hipStream_t stream) {
    const float* z   = (const float*)d_in[0];
    const float* emb = (const float*)d_in[1];
    float* out = (float*)d_out;
    float* ws  = (float*)d_ws;

    int use_embT = (ws_size >= (size_t)WS_NEED_FULL) ? 1 : 0;

    vq_prep<<<1, K_EMB, 0, stream>>>(emb, ws, use_embT);
    vq_main<<<NPOS / 64, 64, 0, stream>>>(z, emb, ws, out, ws + WS_ACC, use_embT);
    vq_finalize<<<1, 1, 0, stream>>>(ws + WS_ACC, out + LOSS_OFF);
}